// Round 4
// baseline (60.214 us; speedup 1.0000x reference)
//
#include <hip/hip_runtime.h>
#include <math.h>

#define NN 512
#define DD 128
#define TEMP_INV (1.0f / 0.07f)
#define EPSF 1e-8f

// ws float-indexed layout:
// [0]           : int ticket (memset to 0 per launch, 4 bytes)
// [16 .. )      : partials float[NN][4] {ral_sum, ral_cnt, oal_sum, oal_cnt}
// [16+4NN .. )  : float sv[NN]  (positions sorted ascending)
// [16+5NN .. )  : int   rk[NN]  (rank of element k in sorted order)
#define WS_PART 16
#define WS_SV   (16 + 4*NN)
#define WS_RK   (16 + 5*NN)

__global__ __launch_bounds__(128) void rank_kernel(
    const float* __restrict__ labels, float* __restrict__ ws)
{
    __shared__ __align__(16) float pos_s[NN];
    const int t = threadIdx.x;
    const int k = blockIdx.x * 128 + t;
    for (int m = t; m < NN; m += 128) pos_s[m] = labels[m & 255];
    __syncthreads();
    const float pk = pos_s[k];
    const float4* p4 = (const float4*)pos_s;
    int r = 0;
    #pragma unroll 8
    for (int q = 0; q < NN / 4; ++q) {
        float4 v = p4[q];
        const int m0 = 4 * q;
        r += (int)(v.x < pk) | ((int)(v.x == pk) & (int)(m0 + 0 < k));
        r += (int)(v.y < pk) | ((int)(v.y == pk) & (int)(m0 + 1 < k));
        r += (int)(v.z < pk) | ((int)(v.z == pk) & (int)(m0 + 2 < k));
        r += (int)(v.w < pk) | ((int)(v.w == pk) & (int)(m0 + 3 < k));
    }
    ws[WS_SV + r] = pk;                 // unique slot (stable tie-break)
    ((int*)ws)[WS_RK + k] = r;
}

// One block (512 threads) per row i. Thread t is both k=t and j=t.
// Fused: per-row sqn/proj/vn, sim/es, OAL term, sorted prefix scan,
// binary-search denominators, RAL term, block reduce, last-block final.
__global__ __launch_bounds__(512) void main_kernel(
    const float* __restrict__ features,
    const float* __restrict__ labels,
    const float* __restrict__ v_prog,
    float* __restrict__ ws,
    float* __restrict__ out)
{
    __shared__ __align__(16) float cfi_s[DD];
    __shared__ __align__(16) float vp_s[DD];
    __shared__ float pos_s[NN];
    __shared__ float sqn_s[NN];
    __shared__ float proj_s[NN];
    __shared__ float sv_s[NN];
    __shared__ float esS[NN];
    __shared__ float wtot[8];
    __shared__ float red_s[32];
    __shared__ double dred[32];
    __shared__ int is_last;

    const int i = blockIdx.x;
    const int t = threadIdx.x;

    if (t < DD) {
        cfi_s[t] = features[(i & 255) * (2 * DD) + (i >> 8) * DD + t];
        vp_s[t]  = v_prog[t];
    }
    pos_s[t] = labels[t & 255];
    sv_s[t]  = ws[WS_SV + t];
    const int rk = ((const int*)ws)[WS_RK + t];
    __syncthreads();

    // ---- fused dot/sqn/proj/vsq over row k = t
    const float4* rowk = (const float4*)(features + (t & 255) * (2 * DD) + (t >> 8) * DD);
    const float4* c4 = (const float4*)cfi_s;
    const float4* v4 = (const float4*)vp_s;
    float d0=0.f,d1=0.f,d2=0.f,d3=0.f;   // dot(row_t, row_i)
    float s0=0.f,s1=0.f,s2=0.f,s3=0.f;   // ||row_t||^2
    float p0=0.f,p1=0.f,p2=0.f,p3=0.f;   // row_t . v_prog
    float g0=0.f,g1=0.f,g2=0.f,g3=0.f;   // ||v_prog||^2
    #pragma unroll 4
    for (int q = 0; q < DD / 4; ++q) {
        float4 a = rowk[q]; float4 c = c4[q]; float4 v = v4[q];
        d0 += a.x*c.x; d1 += a.y*c.y; d2 += a.z*c.z; d3 += a.w*c.w;
        s0 += a.x*a.x; s1 += a.y*a.y; s2 += a.z*a.z; s3 += a.w*a.w;
        p0 += a.x*v.x; p1 += a.y*v.y; p2 += a.z*v.z; p3 += a.w*v.w;
        g0 += v.x*v.x; g1 += v.y*v.y; g2 += v.z*v.z; g3 += v.w*v.w;
    }
    const float dot    = (d0+d1)+(d2+d3);
    const float sqn_k  = (s0+s1)+(s2+s3);
    const float proj_k = (p0+p1)+(p2+p3);
    const float vn     = sqrtf((g0+g1)+(g2+g3)) + EPSF;
    sqn_s[t]  = sqn_k;
    proj_s[t] = proj_k;
    __syncthreads();

    const float sqn_i  = sqn_s[i];
    const float proj_i = proj_s[i];
    const float inv_ni = 1.0f / fmaxf(sqrtf(sqn_i), 1e-12f);
    const float inv_nk = 1.0f / fmaxf(sqrtf(sqn_k), 1e-12f);
    const float sim    = dot * inv_ni * inv_nk * TEMP_INV;
    const float pos_i  = pos_s[i];
    const float pos_k  = pos_s[t];
    const float es     = (t == i) ? 0.0f : __expf(sim);   // k==i excluded
    esS[rk] = es;                                          // scatter to sorted slot

    float oal_sum = 0.f, oal_cnt = 0.f;
    if (pos_i < pos_k) {
        float sqd  = fmaxf(sqn_i + sqn_k - 2.0f * dot, 0.0f);
        float dist = sqrtf(fmaxf(sqd, 1e-24f));
        oal_sum = (proj_k - proj_i) / (vn * fmaxf(dist, 1e-12f));
        oal_cnt = 1.0f;
    }
    __syncthreads();

    // ---- inclusive prefix scan of esS[512]
    float s = esS[t];
    #pragma unroll
    for (int off = 1; off < 64; off <<= 1) {
        float u = __shfl_up(s, off);
        if ((t & 63) >= off) s += u;
    }
    const int wid = t >> 6;
    if ((t & 63) == 63) wtot[wid] = s;
    __syncthreads();
    float woff = 0.f;
    for (int w = 0; w < wid; ++w) woff += wtot[w];   // wid is wave-uniform
    esS[t] = s + woff;
    __syncthreads();
    const float total = esS[NN - 1];

    // ---- denom via interval [lo,hi) of {k : |p_i - p_k| < thr}
    const float thr = fabsf(pos_i - pos_k);          // pd[i][j], j==t

    int R = 0;                                        // first r with sv[r] >= pos_i
    #pragma unroll
    for (int step = 256; step > 0; step >>= 1)
        if (R + step <= NN && sv_s[R + step - 1] < pos_i) R += step;
    int lo = 0;                                       // first r in [0,R) with pd < thr
    #pragma unroll
    for (int step = 256; step > 0; step >>= 1)
        if (lo + step <= R && !(fabsf(pos_i - sv_s[lo + step - 1]) < thr)) lo += step;
    int hi = R;                                       // first r in [R,NN) with pd >= thr
    #pragma unroll
    for (int step = 256; step > 0; step >>= 1)
        if (hi + step <= NN && (fabsf(pos_i - sv_s[hi + step - 1]) < thr)) hi += step;

    const float pe_lo = (lo > 0) ? esS[lo - 1] : 0.0f;
    const float pe_hi = (hi > 0) ? esS[hi - 1] : 0.0f;
    float ral_sum = 0.f, ral_cnt = 0.f;
    if (t != i) {
        // denom >= es_j mathematically (k=j is in the set); clamp guards rounding
        float denom = fmaxf(pe_lo + (total - pe_hi), es);
        const float sw = 1.0f / (1.0f + __expf(-thr));       // sigmoid(pd)
        ral_sum = (__logf(denom + EPSF) - sim) * sw;         // -log(es/(denom+eps))
        ral_cnt = 1.0f;
    }

    // ---- block reduce {ral_sum, ral_cnt, oal_sum, oal_cnt}
    #pragma unroll
    for (int o = 32; o > 0; o >>= 1) {
        ral_sum += __shfl_down(ral_sum, o);
        ral_cnt += __shfl_down(ral_cnt, o);
        oal_sum += __shfl_down(oal_sum, o);
        oal_cnt += __shfl_down(oal_cnt, o);
    }
    if ((t & 63) == 0) {
        red_s[wid*4+0] = ral_sum; red_s[wid*4+1] = ral_cnt;
        red_s[wid*4+2] = oal_sum; red_s[wid*4+3] = oal_cnt;
    }
    __syncthreads();
    if (t == 0) {
        float rs = 0.f, rc = 0.f, os = 0.f, oc = 0.f;
        #pragma unroll
        for (int w = 0; w < 8; ++w) {
            rs += red_s[w*4+0]; rc += red_s[w*4+1];
            os += red_s[w*4+2]; oc += red_s[w*4+3];
        }
        float* pp = ws + WS_PART + i * 4;
        pp[0] = rs; pp[1] = rc; pp[2] = os; pp[3] = oc;
        __threadfence();                                  // release partials device-wide
        int old = __hip_atomic_fetch_add((int*)ws, 1, __ATOMIC_ACQ_REL,
                                         __HIP_MEMORY_SCOPE_AGENT);
        is_last = (old == NN - 1);
    }
    __syncthreads();

    // ---- last block: final reduction (fixed order -> deterministic)
    if (is_last) {
        float* pp = ws + WS_PART + t * 4;
        double rs = (double)__hip_atomic_load(&pp[0], __ATOMIC_RELAXED, __HIP_MEMORY_SCOPE_AGENT);
        double rc = (double)__hip_atomic_load(&pp[1], __ATOMIC_RELAXED, __HIP_MEMORY_SCOPE_AGENT);
        double os = (double)__hip_atomic_load(&pp[2], __ATOMIC_RELAXED, __HIP_MEMORY_SCOPE_AGENT);
        double oc = (double)__hip_atomic_load(&pp[3], __ATOMIC_RELAXED, __HIP_MEMORY_SCOPE_AGENT);
        #pragma unroll
        for (int o = 32; o > 0; o >>= 1) {
            rs += __shfl_down(rs, o);
            rc += __shfl_down(rc, o);
            os += __shfl_down(os, o);
            oc += __shfl_down(oc, o);
        }
        if ((t & 63) == 0) {
            dred[wid*4+0] = rs; dred[wid*4+1] = rc;
            dred[wid*4+2] = os; dred[wid*4+3] = oc;
        }
        __syncthreads();
        if (t == 0) {
            double RS = 0, RC = 0, OS = 0, OC = 0;
            #pragma unroll
            for (int w = 0; w < 8; ++w) {
                RS += dred[w*4+0]; RC += dred[w*4+1];
                OS += dred[w*4+2]; OC += dred[w*4+3];
            }
            double ral = (RC > 0.0) ? RS / RC : 0.0;
            double oal = (OC > 0.0) ? -(OS / OC) : 0.0;
            out[0] = (float)(ral + oal);
        }
    }
}

extern "C" void kernel_launch(void* const* d_in, const int* in_sizes, int n_in,
                              void* d_out, int out_size, void* d_ws, size_t ws_size,
                              hipStream_t stream) {
    const float* features = (const float*)d_in[0];
    const float* labels   = (const float*)d_in[1];
    const float* v_prog   = (const float*)d_in[2];
    float* ws  = (float*)d_ws;
    float* out = (float*)d_out;

    hipMemsetAsync(d_ws, 0, 4, stream);   // zero the ticket each launch
    hipLaunchKernelGGL(rank_kernel, dim3(4),  dim3(128), 0, stream, labels, ws);
    hipLaunchKernelGGL(main_kernel, dim3(NN), dim3(512), 0, stream,
                       features, labels, v_prog, ws, out);
}

// Round 5
// 53.981 us; speedup vs baseline: 1.1155x; 1.1155x over previous
//
#include <hip/hip_runtime.h>
#include <math.h>

#define NN 512
#define DD 128
#define TEMP_INV (1.0f / 0.07f)
#define EPSF 1e-8f

// ws float-indexed layout:
// [0]           : uint ticket (never reset; modulo-NN last-block detection)
// [16 .. )      : partials float[NN][4] {ral_sum, ral_cnt, oal_sum, oal_cnt}
// [16+4NN .. )  : float sv[NN]  (positions sorted ascending)
// [16+5NN .. )  : int   rk[NN]  (rank of element k in sorted order)
#define WS_PART 16
#define WS_SV   (16 + 4*NN)
#define WS_RK   (16 + 5*NN)

__global__ __launch_bounds__(128) void rank_kernel(
    const float* __restrict__ labels, float* __restrict__ ws)
{
    __shared__ __align__(16) float pos_s[NN];
    const int t = threadIdx.x;
    const int k = blockIdx.x * 128 + t;
    for (int m = t; m < NN; m += 128) pos_s[m] = labels[m & 255];
    __syncthreads();
    const float pk = pos_s[k];
    const float4* p4 = (const float4*)pos_s;
    int r = 0;
    #pragma unroll 8
    for (int q = 0; q < NN / 4; ++q) {
        float4 v = p4[q];
        const int m0 = 4 * q;
        r += (int)(v.x < pk) | ((int)(v.x == pk) & (int)(m0 + 0 < k));
        r += (int)(v.y < pk) | ((int)(v.y == pk) & (int)(m0 + 1 < k));
        r += (int)(v.z < pk) | ((int)(v.z == pk) & (int)(m0 + 2 < k));
        r += (int)(v.w < pk) | ((int)(v.w == pk) & (int)(m0 + 3 < k));
    }
    ws[WS_SV + r] = pk;                 // unique slot (stable tie-break)
    ((int*)ws)[WS_RK + k] = r;
}

// One block (512 threads) per row i. Thread t is both k=t and j=t.
// Fused: per-row sqn/proj/vn, sim/es, OAL term, sorted prefix scan,
// binary-search denominators, RAL term, block reduce, last-block final.
__global__ __launch_bounds__(512) void main_kernel(
    const float* __restrict__ features,
    const float* __restrict__ labels,
    const float* __restrict__ v_prog,
    float* __restrict__ ws,
    float* __restrict__ out)
{
    __shared__ __align__(16) float cfi_s[DD];
    __shared__ __align__(16) float vp_s[DD];
    __shared__ float pos_s[NN];
    __shared__ float sqn_s[NN];
    __shared__ float proj_s[NN];
    __shared__ float sv_s[NN];
    __shared__ float esS[NN];
    __shared__ float wtot[8];
    __shared__ float red_s[32];
    __shared__ double dred[32];
    __shared__ int is_last;

    const int i = blockIdx.x;
    const int t = threadIdx.x;

    if (t < DD) {
        cfi_s[t] = features[(i & 255) * (2 * DD) + (i >> 8) * DD + t];
        vp_s[t]  = v_prog[t];
    }
    pos_s[t] = labels[t & 255];
    sv_s[t]  = ws[WS_SV + t];
    const int rk = ((const int*)ws)[WS_RK + t];
    __syncthreads();

    // ---- fused dot/sqn/proj/vsq over row k = t
    const float4* rowk = (const float4*)(features + (t & 255) * (2 * DD) + (t >> 8) * DD);
    const float4* c4 = (const float4*)cfi_s;
    const float4* v4 = (const float4*)vp_s;
    float d0=0.f,d1=0.f,d2=0.f,d3=0.f;   // dot(row_t, row_i)
    float s0=0.f,s1=0.f,s2=0.f,s3=0.f;   // ||row_t||^2
    float p0=0.f,p1=0.f,p2=0.f,p3=0.f;   // row_t . v_prog
    float g0=0.f,g1=0.f,g2=0.f,g3=0.f;   // ||v_prog||^2
    #pragma unroll 4
    for (int q = 0; q < DD / 4; ++q) {
        float4 a = rowk[q]; float4 c = c4[q]; float4 v = v4[q];
        d0 += a.x*c.x; d1 += a.y*c.y; d2 += a.z*c.z; d3 += a.w*c.w;
        s0 += a.x*a.x; s1 += a.y*a.y; s2 += a.z*a.z; s3 += a.w*a.w;
        p0 += a.x*v.x; p1 += a.y*v.y; p2 += a.z*v.z; p3 += a.w*v.w;
        g0 += v.x*v.x; g1 += v.y*v.y; g2 += v.z*v.z; g3 += v.w*v.w;
    }
    const float dot    = (d0+d1)+(d2+d3);
    const float sqn_k  = (s0+s1)+(s2+s3);
    const float proj_k = (p0+p1)+(p2+p3);
    const float vn     = sqrtf((g0+g1)+(g2+g3)) + EPSF;
    sqn_s[t]  = sqn_k;
    proj_s[t] = proj_k;
    __syncthreads();

    const float sqn_i  = sqn_s[i];
    const float proj_i = proj_s[i];
    const float inv_ni = 1.0f / fmaxf(sqrtf(sqn_i), 1e-12f);
    const float inv_nk = 1.0f / fmaxf(sqrtf(sqn_k), 1e-12f);
    const float sim    = dot * inv_ni * inv_nk * TEMP_INV;
    const float pos_i  = pos_s[i];
    const float pos_k  = pos_s[t];
    const float es     = (t == i) ? 0.0f : __expf(sim);   // k==i excluded
    esS[rk] = es;                                          // scatter to sorted slot

    float oal_sum = 0.f, oal_cnt = 0.f;
    if (pos_i < pos_k) {
        float sqd  = fmaxf(sqn_i + sqn_k - 2.0f * dot, 0.0f);
        float dist = sqrtf(fmaxf(sqd, 1e-24f));
        oal_sum = (proj_k - proj_i) / (vn * fmaxf(dist, 1e-12f));
        oal_cnt = 1.0f;
    }
    __syncthreads();

    // ---- inclusive prefix scan of esS[512]
    float s = esS[t];
    #pragma unroll
    for (int off = 1; off < 64; off <<= 1) {
        float u = __shfl_up(s, off);
        if ((t & 63) >= off) s += u;
    }
    const int wid = t >> 6;
    if ((t & 63) == 63) wtot[wid] = s;
    __syncthreads();
    float woff = 0.f;
    for (int w = 0; w < wid; ++w) woff += wtot[w];   // wid is wave-uniform
    esS[t] = s + woff;
    __syncthreads();
    const float total = esS[NN - 1];

    // ---- denom via interval [lo,hi) of {k : |p_i - p_k| < thr}
    const float thr = fabsf(pos_i - pos_k);          // pd[i][j], j==t

    int R = 0;                                        // first r with sv[r] >= pos_i
    #pragma unroll
    for (int step = 256; step > 0; step >>= 1)
        if (R + step <= NN && sv_s[R + step - 1] < pos_i) R += step;
    int lo = 0;                                       // first r in [0,R) with pd < thr
    #pragma unroll
    for (int step = 256; step > 0; step >>= 1)
        if (lo + step <= R && !(fabsf(pos_i - sv_s[lo + step - 1]) < thr)) lo += step;
    int hi = R;                                       // first r in [R,NN) with pd >= thr
    #pragma unroll
    for (int step = 256; step > 0; step >>= 1)
        if (hi + step <= NN && (fabsf(pos_i - sv_s[hi + step - 1]) < thr)) hi += step;

    const float pe_lo = (lo > 0) ? esS[lo - 1] : 0.0f;
    const float pe_hi = (hi > 0) ? esS[hi - 1] : 0.0f;
    float ral_sum = 0.f, ral_cnt = 0.f;
    if (t != i) {
        // denom >= es_j mathematically (k=j is in the set); clamp guards rounding
        float denom = fmaxf(pe_lo + (total - pe_hi), es);
        const float sw = 1.0f / (1.0f + __expf(-thr));       // sigmoid(pd)
        ral_sum = (__logf(denom + EPSF) - sim) * sw;         // -log(es/(denom+eps))
        ral_cnt = 1.0f;
    }

    // ---- block reduce {ral_sum, ral_cnt, oal_sum, oal_cnt}
    #pragma unroll
    for (int o = 32; o > 0; o >>= 1) {
        ral_sum += __shfl_down(ral_sum, o);
        ral_cnt += __shfl_down(ral_cnt, o);
        oal_sum += __shfl_down(oal_sum, o);
        oal_cnt += __shfl_down(oal_cnt, o);
    }
    if ((t & 63) == 0) {
        red_s[wid*4+0] = ral_sum; red_s[wid*4+1] = ral_cnt;
        red_s[wid*4+2] = oal_sum; red_s[wid*4+3] = oal_cnt;
    }
    __syncthreads();
    if (t == 0) {
        float rs = 0.f, rc = 0.f, os = 0.f, oc = 0.f;
        #pragma unroll
        for (int w = 0; w < 8; ++w) {
            rs += red_s[w*4+0]; rc += red_s[w*4+1];
            os += red_s[w*4+2]; oc += red_s[w*4+3];
        }
        float* pp = ws + WS_PART + i * 4;
        pp[0] = rs; pp[1] = rc; pp[2] = os; pp[3] = oc;
        __threadfence();                                  // release partials device-wide
        // modulo ticket: works from ANY initial value (incl. 0xAA poison);
        // 2^32 % NN == 0, so each run of NN increments hits every residue once.
        unsigned old = __hip_atomic_fetch_add((unsigned*)ws, 1u, __ATOMIC_ACQ_REL,
                                              __HIP_MEMORY_SCOPE_AGENT);
        is_last = ((old & (NN - 1u)) == NN - 1u);
    }
    __syncthreads();

    // ---- last block: final reduction (fixed order -> deterministic)
    if (is_last) {
        float* pp = ws + WS_PART + t * 4;
        double rs = (double)__hip_atomic_load(&pp[0], __ATOMIC_RELAXED, __HIP_MEMORY_SCOPE_AGENT);
        double rc = (double)__hip_atomic_load(&pp[1], __ATOMIC_RELAXED, __HIP_MEMORY_SCOPE_AGENT);
        double os = (double)__hip_atomic_load(&pp[2], __ATOMIC_RELAXED, __HIP_MEMORY_SCOPE_AGENT);
        double oc = (double)__hip_atomic_load(&pp[3], __ATOMIC_RELAXED, __HIP_MEMORY_SCOPE_AGENT);
        #pragma unroll
        for (int o = 32; o > 0; o >>= 1) {
            rs += __shfl_down(rs, o);
            rc += __shfl_down(rc, o);
            os += __shfl_down(os, o);
            oc += __shfl_down(oc, o);
        }
        if ((t & 63) == 0) {
            dred[wid*4+0] = rs; dred[wid*4+1] = rc;
            dred[wid*4+2] = os; dred[wid*4+3] = oc;
        }
        __syncthreads();
        if (t == 0) {
            double RS = 0, RC = 0, OS = 0, OC = 0;
            #pragma unroll
            for (int w = 0; w < 8; ++w) {
                RS += dred[w*4+0]; RC += dred[w*4+1];
                OS += dred[w*4+2]; OC += dred[w*4+3];
            }
            double ral = (RC > 0.0) ? RS / RC : 0.0;
            double oal = (OC > 0.0) ? -(OS / OC) : 0.0;
            out[0] = (float)(ral + oal);
        }
    }
}

extern "C" void kernel_launch(void* const* d_in, const int* in_sizes, int n_in,
                              void* d_out, int out_size, void* d_ws, size_t ws_size,
                              hipStream_t stream) {
    const float* features = (const float*)d_in[0];
    const float* labels   = (const float*)d_in[1];
    const float* v_prog   = (const float*)d_in[2];
    float* ws  = (float*)d_ws;
    float* out = (float*)d_out;

    hipLaunchKernelGGL(rank_kernel, dim3(4),  dim3(128), 0, stream, labels, ws);
    hipLaunchKernelGGL(main_kernel, dim3(NN), dim3(512), 0, stream,
                       features, labels, v_prog, ws, out);
}